// Round 4
// baseline (683.145 us; speedup 1.0000x reference)
//
#include <hip/hip_runtime.h>
#include <hip/hip_fp16.h>
#include <cstdint>
#include <cstddef>

#define HIDDEN 2048
#define INTER  4096
#define EPSQ   1e-5f

typedef int v4i __attribute__((ext_vector_type(4)));

__device__ __forceinline__ void async_ld16(const void* g, void* l) {
  __builtin_amdgcn_global_load_lds((const __attribute__((address_space(1))) void*)g,
                                   (__attribute__((address_space(3))) void*)l, 16, 0, 0);
}

#define BAR()   __builtin_amdgcn_s_barrier()
#define VMC(n)  asm volatile("s_waitcnt vmcnt(" #n ")" ::: "memory")

// ---------------- absmean reduction (f64 accumulate, atomic combine) ----------------
__global__ void absmean_kernel(const float* __restrict__ w, size_t n4, double* __restrict__ out) {
  double s = 0.0;
  const float4* w4 = (const float4*)w;
  for (size_t i = blockIdx.x * (size_t)blockDim.x + threadIdx.x; i < n4;
       i += (size_t)gridDim.x * blockDim.x) {
    float4 v = w4[i];
    s += (double)fabsf(v.x) + (double)fabsf(v.y) + (double)fabsf(v.z) + (double)fabsf(v.w);
  }
  #pragma unroll
  for (int o = 32; o; o >>= 1) s += __shfl_down(s, o);
  __shared__ double red[4];
  if ((threadIdx.x & 63) == 0) red[threadIdx.x >> 6] = s;
  __syncthreads();
  if (threadIdx.x == 0) atomicAdd(out, red[0] + red[1] + red[2] + red[3]);
}

// ---------------- weight ternarization: q = clip(round(w/scale), -1, 1) ----------------
__global__ void quantw_kernel(const float* __restrict__ w, size_t n4,
                              const double* __restrict__ sum, double invcnt,
                              int8_t* __restrict__ q) {
  const float scale = (float)fmax(sum[0] * invcnt, (double)EPSQ);
  const float4* w4 = (const float4*)w;
  char4* q4 = (char4*)q;
  for (size_t i = blockIdx.x * (size_t)blockDim.x + threadIdx.x; i < n4;
       i += (size_t)gridDim.x * blockDim.x) {
    float4 v = w4[i];
    char4 c;
    c.x = (signed char)fmaxf(-1.f, fminf(1.f, rintf(v.x / scale)));
    c.y = (signed char)fmaxf(-1.f, fminf(1.f, rintf(v.y / scale)));
    c.z = (signed char)fmaxf(-1.f, fminf(1.f, rintf(v.z / scale)));
    c.w = (signed char)fmaxf(-1.f, fminf(1.f, rintf(v.w / scale)));
    q4[i] = c;
  }
}

// ---------------- FWHT: one wave per token, H_N = H_E(regs) (x) H_64(lanes) ----------------
template <int LOGN, bool HALF_IN>
__global__ void __launch_bounds__(256) fwht_quant_kernel(const void* __restrict__ Xv,
                                                         int8_t* __restrict__ Q,
                                                         float* __restrict__ invs) {
  constexpr int N = 1 << LOGN;
  constexpr int E = N / 64;                     // 32 (2048) or 64 (4096) regs/lane
  const int lane = threadIdx.x & 63;
  const size_t t = (size_t)blockIdx.x * 4 + (threadIdx.x >> 6);

  float r[E];
  if constexpr (HALF_IN) {
    const int4* xp = (const int4*)((const __half*)Xv + t * (size_t)N + lane * E);
    #pragma unroll
    for (int u = 0; u < E / 8; ++u) {
      alignas(16) __half hb[8];
      *(int4*)hb = xp[u];
      #pragma unroll
      for (int j = 0; j < 8; ++j) r[u * 8 + j] = __half2float(hb[j]);
    }
  } else {
    const float4* xp = (const float4*)((const float*)Xv + t * (size_t)N + lane * E);
    #pragma unroll
    for (int u = 0; u < E / 4; ++u) {
      float4 v = xp[u];
      r[u * 4 + 0] = v.x; r[u * 4 + 1] = v.y; r[u * 4 + 2] = v.z; r[u * 4 + 3] = v.w;
    }
  }

  #pragma unroll
  for (int m = 1; m < E; m <<= 1) {
    #pragma unroll
    for (int e = 0; e < E; ++e) {
      if (!(e & m)) {
        float a = r[e], b = r[e | m];
        r[e] = a + b;
        r[e | m] = a - b;
      }
    }
  }
  #pragma unroll
  for (int m = 1; m < 64; m <<= 1) {
    const float sgn = (lane & m) ? -1.f : 1.f;
    #pragma unroll
    for (int e = 0; e < E; ++e) {
      float w = __shfl_xor(r[e], m, 64);
      r[e] = fmaf(r[e], sgn, w);
    }
  }

  float mx = 0.f;
  #pragma unroll
  for (int e = 0; e < E; ++e) mx = fmaxf(mx, fabsf(r[e]));
  #pragma unroll
  for (int m = 1; m < 64; m <<= 1) mx = fmaxf(mx, __shfl_xor(mx, m, 64));

  constexpr float c = (LOGN == 11) ? 0.022097086912079608f : 0.015625f;  // 1/sqrt(N)
  mx = fmaxf(mx * c, EPSQ);
  const float sc = 127.0f * c / mx;
  if (lane == 0) invs[t] = mx * (1.0f / 127.0f);

  alignas(16) int8_t qv[E];
  #pragma unroll
  for (int e = 0; e < E; ++e) {
    float q = rintf(r[e] * sc);
    q = fmaxf(-127.f, fminf(127.f, q));
    qv[e] = (int8_t)q;
  }
  int8_t* qp = Q + t * (size_t)N + lane * E;
  #pragma unroll
  for (int u = 0; u < E / 16; ++u) ((int4*)qp)[u] = ((const int4*)qv)[u];
}

// ---------------- int8 GEMM, 256x256 tile, pipelined cluster schedule ----------------
// 8 waves (2M x 4N), each wave 128x64 output via 8x4 mfma_i32_16x16x64_i8.
// R4: kk-split clusters + one-cluster-ahead register prefetch + 6 barriers/iter.
//   Each K-tile (128 B) = 8 clusters of 8 MFMA, quadrant snake
//   (00,01,11,10)k0 -> (10,11,01,00)k1. Fragments: aA/aB (4x b128 = 16 reg),
//   bA/bB (2x b128 = 8 reg) = 48 frag regs; ds_reads for cluster k+1 issue
//   BEFORE cluster k's MFMAs -> LDS-read port drains under the matrix pipe.
//   Raw s_barrier does NOT drain lgkm, so prefetches stay in flight across
//   barriers; compiler inserts exact per-operand lgkm waits.
// Barriers (6/iter): B1 post-c6 (buf0.B reads done -> SB ok), B2 post-c7
//   (buf0.A done -> SA ok), B3 = vmcnt(8) gate (prev-staged buf1 landed;
//   all-waves), B4/B5/B6 mirror for buf1. vmcnt(8) with 16 outstanding waits
//   the 8 oldest = the buffer being opened; every gated load has >= 4-phase
//   flight. Last iter: no stages, gates drain with vmcnt(0) at B3.
template <bool RELU2, typename TOUT>
__global__ __launch_bounds__(512, 2)
void gemm_i8_8ph(const int8_t* __restrict__ A, const int8_t* __restrict__ B,
                 TOUT* __restrict__ C, const float* __restrict__ invs,
                 const double* __restrict__ wsum, double invcnt,
                 int N, int K) {
  __shared__ int8_t As[2 * 2 * 128 * 128];
  __shared__ int8_t Bs[2 * 2 * 128 * 128];

  // T1: XCD-aware chunked swizzle (nwg % 8 == 0 for all launches here)
  const int GX = N >> 8;
  const int nwg = gridDim.x;
  int wg = blockIdx.x;
  wg = (wg & 7) * (nwg >> 3) + (wg >> 3);
  const int bx = wg % GX;
  const int by = wg / GX;
  const int m0 = by * 256, n0 = bx * 256;

  const int t = threadIdx.x;
  const int lane = t & 63;
  const int wave = t >> 6;
  const int wr = wave >> 2;  // 0..1 (M)
  const int wc = wave & 3;   // 0..3 (N)

  // ---- staging: global source pre-swizzled, LDS dest linear (rule: both-or-neither)
  const int row0 = t >> 3;                                  // 0..63
  const int colsw = ((t & 7) * 16) ^ ((row0 & 7) << 4);
  const int8_t* gA0 = A + (size_t)(m0 + row0) * K + colsw;
  const int8_t* gA1 = gA0 + (size_t)128 * K;
  const int8_t* gB0 = B + (size_t)(n0 + row0) * K + colsw;
  const int8_t* gB1 = gB0 + (size_t)128 * K;
  const size_t rstep = (size_t)64 * K;

  auto SA = [&](int bf, int hf, int kt) {
    const int8_t* g = (hf ? gA1 : gA0) + (size_t)kt * 128;
    int8_t* l = As + bf * 32768 + hf * 16384 + t * 16;
    async_ld16(g, l);
    async_ld16(g + rstep, l + 8192);
  };
  auto SB = [&](int bf, int hf, int kt) {
    const int8_t* g = (hf ? gB1 : gB0) + (size_t)kt * 128;
    int8_t* l = Bs + bf * 32768 + hf * 16384 + t * 16;
    async_ld16(g, l);
    async_ld16(g + rstep, l + 8192);
  };

  // ---- swizzled ds_read addressing: row&7 == lane&7 for every fragment row
  const int csw0 = ((lane >> 4) * 16) ^ ((lane & 7) << 4);        // kk = 0
  const int csw1 = (64 + (lane >> 4) * 16) ^ ((lane & 7) << 4);   // kk = 1
  const int8_t* pA0 = As + wr * 16384 + (lane & 15) * 128;
  const int8_t* pB0 = Bs + (wc >> 1) * 16384 + ((wc & 1) * 64 + (lane & 15)) * 128;

  v4i acc[8][4] = {};
  v4i aA[4], aB[4], bA[2], bB[2];

  auto RDa = [&](v4i (&af)[4], int bf, int m4, int kk) {
    const int8_t* p = pA0 + bf * 32768 + m4 * 8192;
    const int cs = kk ? csw1 : csw0;
    #pragma unroll
    for (int mt = 0; mt < 4; ++mt) af[mt] = *(const v4i*)(p + mt * 2048 + cs);
  };
  auto RDb = [&](v4i (&bf)[2], int buf, int n2, int kk) {
    const int8_t* p = pB0 + buf * 32768 + n2 * 4096;
    const int cs = kk ? csw1 : csw0;
    #pragma unroll
    for (int nt = 0; nt < 2; ++nt) bf[nt] = *(const v4i*)(p + nt * 2048 + cs);
  };
  auto MMC = [&](int m4, int n2, v4i (&af)[4], v4i (&bf)[2]) {  // 8-MFMA cluster (T5)
    __builtin_amdgcn_s_setprio(1);
    #pragma unroll
    for (int mt = 0; mt < 4; ++mt)
      #pragma unroll
      for (int nt = 0; nt < 2; ++nt)
        acc[m4 * 4 + mt][n2 * 2 + nt] =
            __builtin_amdgcn_mfma_i32_16x16x64_i8(af[mt], bf[nt], acc[m4 * 4 + mt][n2 * 2 + nt], 0, 0, 0);
    __builtin_amdgcn_s_setprio(0);
  };

  const int NIT = K >> 8;  // 2 K-tiles (256 bytes of K) per iteration; NIT >= 8 here

  // prologue: stage tile0 -> buf0 (8 loads) then tile1 -> buf1 (8 loads);
  // vmcnt(8) waits the 8 oldest (= buf0); then prefetch c1 operands.
  SB(0, 0, 0); SB(0, 1, 0); SA(0, 0, 0); SA(0, 1, 0);
  SB(1, 0, 1); SB(1, 1, 1); SA(1, 0, 1); SA(1, 1, 1);
  VMC(8);
  BAR();
  RDa(aA, 0, 0, 0); RDb(bA, 0, 0, 0);

  for (int it = 0; it < NIT; ++it) {
    const int kt2 = 2 * it + 2, kt3 = 2 * it + 3;
    const bool more = it < NIT - 1;

    // -------- buf0 K-tile --------
    RDb(bB, 0, 1, 0);                       MMC(0, 0, aA, bA);   // c1 (0,0)k0
    RDa(aB, 0, 1, 0);                       MMC(0, 1, aA, bB);   // c2 (0,1)k0
                                            MMC(1, 1, aB, bB);   // c3 (1,1)k0
    RDa(aA, 0, 1, 1); RDb(bB, 0, 0, 1);     MMC(1, 0, aB, bA);   // c4 (1,0)k0
    RDb(bA, 0, 1, 1);                       MMC(1, 0, aA, bB);   // c5 (1,0)k1
    RDa(aB, 0, 0, 1);                       MMC(1, 1, aA, bA);   // c6 (1,1)k1
    BAR();                                                        // B1: buf0.B reads done
    if (more) { SB(0, 0, kt2); SB(0, 1, kt2); }
                                            MMC(0, 1, aB, bA);   // c7 (0,1)k1
    BAR();                                                        // B2: buf0.A reads done
    if (more) { SA(0, 0, kt2); SA(0, 1, kt2); VMC(8); } else { VMC(0); }
    BAR();                                                        // B3: buf1 landed (all waves)
    RDa(aA, 1, 0, 0); RDb(bA, 1, 0, 0);     MMC(0, 0, aB, bB);   // c8 (0,0)k1 + buf1 pf

    // -------- buf1 K-tile --------
    RDb(bB, 1, 1, 0);                       MMC(0, 0, aA, bA);   // c9
    RDa(aB, 1, 1, 0);                       MMC(0, 1, aA, bB);   // c10
                                            MMC(1, 1, aB, bB);   // c11
    RDa(aA, 1, 1, 1); RDb(bB, 1, 0, 1);     MMC(1, 0, aB, bA);   // c12
    RDb(bA, 1, 1, 1);                       MMC(1, 0, aA, bB);   // c13
    RDa(aB, 1, 0, 1);                       MMC(1, 1, aA, bA);   // c14
    BAR();                                                        // B4: buf1.B reads done
    if (more) { SB(1, 0, kt3); SB(1, 1, kt3); }
                                            MMC(0, 1, aB, bA);   // c15
    BAR();                                                        // B5: buf1.A reads done
    if (more) { SA(1, 0, kt3); SA(1, 1, kt3); VMC(8); } else { VMC(0); }
    BAR();                                                        // B6: buf0' landed (all waves)
    if (more) { RDa(aA, 0, 0, 0); RDb(bA, 0, 0, 0); }            // next-iter c1 pf
                                            MMC(0, 0, aB, bB);   // c16
  }

  // ---- epilogue: C/D layout (16x16): col = lane&15, row = (lane>>4)*4 + reg
  const float wscale = (float)fmax(wsum[0] * invcnt, (double)EPSQ);
  const int crow_base = m0 + wr * 128 + (lane >> 4) * 4;
  const int ccol_base = n0 + wc * 64 + (lane & 15);
  #pragma unroll
  for (int mt = 0; mt < 8; ++mt) {
    const int trow = crow_base + mt * 16;
    float fr[4];
    #pragma unroll
    for (int r = 0; r < 4; ++r) fr[r] = wscale * invs[trow + r];
    #pragma unroll
    for (int nt = 0; nt < 4; ++nt) {
      const int col = ccol_base + nt * 16;
      #pragma unroll
      for (int r = 0; r < 4; ++r) {
        float v = (float)acc[mt][nt][r] * fr[r];
        if (RELU2) v = v > 0.f ? v * v : 0.f;
        if constexpr (sizeof(TOUT) == 2)
          C[(size_t)(trow + r) * N + col] = __float2half(v);
        else
          C[(size_t)(trow + r) * N + col] = v;
      }
    }
  }
}

extern "C" void kernel_launch(void* const* d_in, const int* in_sizes, int n_in,
                              void* d_out, int out_size, void* d_ws, size_t ws_size,
                              hipStream_t stream) {
  const float* x      = (const float*)d_in[0];   // (4,4096,2048)
  const float* w_up   = (const float*)d_in[1];   // (4096,2048)
  const float* w_down = (const float*)d_in[2];   // (2048,4096)
  float* out = (float*)d_out;

  const int T = in_sizes[0] / HIDDEN;            // 16384 tokens
  const size_t WN = (size_t)INTER * HIDDEN;      // 8388608 weights per matrix

  char* ws = (char*)d_ws;
  double* sums   = (double*)ws;                                   // [2]
  float* invs1   = (float*)(ws + 256);                            // [T]
  float* invs2   = (float*)(ws + 256 + 65536);                    // [T]
  int8_t* wq_up  = (int8_t*)(ws + 131328);                        // 8 MB
  int8_t* wq_dn  = wq_up + WN;                                    // 8 MB
  int8_t* a8_1   = wq_dn + WN;                                    // T*2048
  int8_t* a8_2   = a8_1 + (size_t)T * HIDDEN;                     // T*4096
  __half* h      = (__half*)(a8_2 + (size_t)T * INTER);           // T*4096 fp16

  const double invcnt = 1.0 / (double)WN;

  hipMemsetAsync(sums, 0, 256, stream);
  absmean_kernel<<<1024, 256, 0, stream>>>(w_up, WN / 4, sums + 0);
  absmean_kernel<<<1024, 256, 0, stream>>>(w_down, WN / 4, sums + 1);
  quantw_kernel<<<2048, 256, 0, stream>>>(w_up, WN / 4, sums + 0, invcnt, wq_up);
  quantw_kernel<<<2048, 256, 0, stream>>>(w_down, WN / 4, sums + 1, invcnt, wq_dn);

  fwht_quant_kernel<11, false><<<T / 4, 256, 0, stream>>>(x, a8_1, invs1);
  gemm_i8_8ph<true, __half><<<(T / 256) * (INTER / 256), 512, 0, stream>>>(
      a8_1, wq_up, h, invs1, sums + 0, invcnt, INTER, HIDDEN);
  fwht_quant_kernel<12, true><<<T / 4, 256, 0, stream>>>(h, a8_2, invs2);
  gemm_i8_8ph<false, float><<<(T / 256) * (HIDDEN / 256), 512, 0, stream>>>(
      a8_2, wq_dn, out, invs2, sums + 1, invcnt, HIDDEN, INTER);
}

// Round 5
// 679.264 us; speedup vs baseline: 1.0057x; 1.0057x over previous
//
#include <hip/hip_runtime.h>
#include <hip/hip_fp16.h>
#include <cstdint>
#include <cstddef>

#define HIDDEN 2048
#define INTER  4096
#define EPSQ   1e-5f

typedef int v4i __attribute__((ext_vector_type(4)));

__device__ __forceinline__ void async_ld16(const void* g, void* l) {
  __builtin_amdgcn_global_load_lds((const __attribute__((address_space(1))) void*)g,
                                   (__attribute__((address_space(3))) void*)l, 16, 0, 0);
}

#define BAR()   __builtin_amdgcn_s_barrier()
#define VMC(n)  asm volatile("s_waitcnt vmcnt(" #n ")" ::: "memory")

// ---------------- absmean reduction (f64 accumulate, atomic combine) ----------------
__global__ void absmean_kernel(const float* __restrict__ w, size_t n4, double* __restrict__ out) {
  double s = 0.0;
  const float4* w4 = (const float4*)w;
  for (size_t i = blockIdx.x * (size_t)blockDim.x + threadIdx.x; i < n4;
       i += (size_t)gridDim.x * blockDim.x) {
    float4 v = w4[i];
    s += (double)fabsf(v.x) + (double)fabsf(v.y) + (double)fabsf(v.z) + (double)fabsf(v.w);
  }
  #pragma unroll
  for (int o = 32; o; o >>= 1) s += __shfl_down(s, o);
  __shared__ double red[4];
  if ((threadIdx.x & 63) == 0) red[threadIdx.x >> 6] = s;
  __syncthreads();
  if (threadIdx.x == 0) atomicAdd(out, red[0] + red[1] + red[2] + red[3]);
}

// ---------------- weight ternarization: q = clip(round(w/scale), -1, 1) ----------------
__global__ void quantw_kernel(const float* __restrict__ w, size_t n4,
                              const double* __restrict__ sum, double invcnt,
                              int8_t* __restrict__ q) {
  const float scale = (float)fmax(sum[0] * invcnt, (double)EPSQ);
  const float4* w4 = (const float4*)w;
  char4* q4 = (char4*)q;
  for (size_t i = blockIdx.x * (size_t)blockDim.x + threadIdx.x; i < n4;
       i += (size_t)gridDim.x * blockDim.x) {
    float4 v = w4[i];
    char4 c;
    c.x = (signed char)fmaxf(-1.f, fminf(1.f, rintf(v.x / scale)));
    c.y = (signed char)fmaxf(-1.f, fminf(1.f, rintf(v.y / scale)));
    c.z = (signed char)fmaxf(-1.f, fminf(1.f, rintf(v.z / scale)));
    c.w = (signed char)fmaxf(-1.f, fminf(1.f, rintf(v.w / scale)));
    q4[i] = c;
  }
}

// ---------------- FWHT: one wave per token, H_N = H_E(regs) (x) H_64(lanes) ----------------
template <int LOGN, bool HALF_IN>
__global__ void __launch_bounds__(256) fwht_quant_kernel(const void* __restrict__ Xv,
                                                         int8_t* __restrict__ Q,
                                                         float* __restrict__ invs) {
  constexpr int N = 1 << LOGN;
  constexpr int E = N / 64;                     // 32 (2048) or 64 (4096) regs/lane
  const int lane = threadIdx.x & 63;
  const size_t t = (size_t)blockIdx.x * 4 + (threadIdx.x >> 6);

  float r[E];
  if constexpr (HALF_IN) {
    const int4* xp = (const int4*)((const __half*)Xv + t * (size_t)N + lane * E);
    #pragma unroll
    for (int u = 0; u < E / 8; ++u) {
      alignas(16) __half hb[8];
      *(int4*)hb = xp[u];
      #pragma unroll
      for (int j = 0; j < 8; ++j) r[u * 8 + j] = __half2float(hb[j]);
    }
  } else {
    const float4* xp = (const float4*)((const float*)Xv + t * (size_t)N + lane * E);
    #pragma unroll
    for (int u = 0; u < E / 4; ++u) {
      float4 v = xp[u];
      r[u * 4 + 0] = v.x; r[u * 4 + 1] = v.y; r[u * 4 + 2] = v.z; r[u * 4 + 3] = v.w;
    }
  }

  #pragma unroll
  for (int m = 1; m < E; m <<= 1) {
    #pragma unroll
    for (int e = 0; e < E; ++e) {
      if (!(e & m)) {
        float a = r[e], b = r[e | m];
        r[e] = a + b;
        r[e | m] = a - b;
      }
    }
  }
  #pragma unroll
  for (int m = 1; m < 64; m <<= 1) {
    const float sgn = (lane & m) ? -1.f : 1.f;
    #pragma unroll
    for (int e = 0; e < E; ++e) {
      float w = __shfl_xor(r[e], m, 64);
      r[e] = fmaf(r[e], sgn, w);
    }
  }

  float mx = 0.f;
  #pragma unroll
  for (int e = 0; e < E; ++e) mx = fmaxf(mx, fabsf(r[e]));
  #pragma unroll
  for (int m = 1; m < 64; m <<= 1) mx = fmaxf(mx, __shfl_xor(mx, m, 64));

  constexpr float c = (LOGN == 11) ? 0.022097086912079608f : 0.015625f;  // 1/sqrt(N)
  mx = fmaxf(mx * c, EPSQ);
  const float sc = 127.0f * c / mx;
  if (lane == 0) invs[t] = mx * (1.0f / 127.0f);

  alignas(16) int8_t qv[E];
  #pragma unroll
  for (int e = 0; e < E; ++e) {
    float q = rintf(r[e] * sc);
    q = fmaxf(-127.f, fminf(127.f, q));
    qv[e] = (int8_t)q;
  }
  int8_t* qp = Q + t * (size_t)N + lane * E;
  #pragma unroll
  for (int u = 0; u < E / 16; ++u) ((int4*)qp)[u] = ((const int4*)qv)[u];
}

// ---------------- int8 GEMM, 256x256 tile, BK=64, 3-buffer uniform-phase ring -------
// 8 waves (2M x 4N), wave out 128x64. One 64-B K-tile = 2 phases of 16 MFMA:
//   even: RD A(mt0-3)+B(nt0-3) [8 ds_read_b128]; stage SA(kt+2) [2 gloads]
//   odd : RD A(mt4-7)          [4 ds_read_b128]; stage SB(kt+2) [2 gloads]; gate
// Every phase: {reads; stage; [VMC]} BAR [compiler lgkm waits] MM16 BAR.
// 3 buffers (A,B 16 KB each; 96 KiB total): staged loads get 3-4 phase flight;
// gate VMC(4) once per K-tile drains the 4 oldest (= next buffer) keeping the
// 4 newest in flight. Gate-BAR sits one full MFMA region before the first read
// of the opened buffer. WAR: buffer stageable the K-tile after its last read
// (reader's compiler lgkm wait before MM -> reads complete before closing BAR).
// LDS swizzle for 64-B rows: chunk ^= (row>>1)&3 -> wave b128 reads are 2-way
// bank-aliased (free, m136). Stage source pre-swizzled, LDS dest linear.
template <bool RELU2, typename TOUT>
__global__ __launch_bounds__(512, 2)
void gemm_i8_3buf(const int8_t* __restrict__ A, const int8_t* __restrict__ B,
                  TOUT* __restrict__ C, const float* __restrict__ invs,
                  const double* __restrict__ wsum, double invcnt,
                  int N, int K) {
  __shared__ int8_t As[3 * 16384];
  __shared__ int8_t Bs[3 * 16384];

  // T1: XCD-aware chunked swizzle (nwg % 8 == 0 for all launches here)
  const int GX = N >> 8;
  const int nwg = gridDim.x;
  int wg = blockIdx.x;
  wg = (wg & 7) * (nwg >> 3) + (wg >> 3);
  const int bx = wg % GX;
  const int by = wg / GX;
  const int m0 = by * 256, n0 = bx * 256;

  const int t = threadIdx.x;
  const int lane = t & 63;
  const int wave = t >> 6;
  const int wr = wave >> 2;  // 0..1 (M)
  const int wc = wave & 3;   // 0..3 (N)

  // ---- staging: thread t covers (row = t>>2 [+128], chunk_l = t&3) of a 256x64 tile.
  // global source column pre-swizzled: chunk_g = chunk_l ^ ((row>>1)&3) = (t&3)^((t>>3)&3)
  const int srow = t >> 2;
  const int scol = (((t & 3) ^ ((t >> 3) & 3)) << 4);
  const int8_t* gA = A + (size_t)(m0 + srow) * K + scol;
  const int8_t* gB = B + (size_t)(n0 + srow) * K + scol;
  const size_t rstep = (size_t)128 * K;
  int8_t* lA = As + t * 16;
  int8_t* lB = Bs + t * 16;

  auto SA = [&](int buf, int kt) {
    const int8_t* g = gA + (size_t)kt * 64;
    async_ld16(g, lA + buf * 16384);
    async_ld16(g + rstep, lA + buf * 16384 + 8192);
  };
  auto SB = [&](int buf, int kt) {
    const int8_t* g = gB + (size_t)kt * 64;
    async_ld16(g, lB + buf * 16384);
    async_ld16(g + rstep, lB + buf * 16384 + 8192);
  };

  // ---- swizzled fragment reads: lane holds row = base + (lane&15), k-chunk = lane>>4.
  // LDS chunk = (lane>>4) ^ ((row>>1)&3); base rows are multiples of 16 so
  // (row>>1)&3 == ((lane&15)>>1)&3 == (lane>>1)&3 -> per-thread constant.
  const int chunk_l = ((lane >> 4) ^ ((lane >> 1) & 3)) << 4;
  const int8_t* pA = As + (wr * 128 + (lane & 15)) * 64 + chunk_l;
  const int8_t* pB = Bs + (wc * 64 + (lane & 15)) * 64 + chunk_l;

  v4i acc[8][4] = {};
  v4i a[4], b[4];

  auto RDA = [&](int buf, int m4) {
    const int8_t* p = pA + buf * 16384 + m4 * 4096;
    #pragma unroll
    for (int mt = 0; mt < 4; ++mt) a[mt] = *(const v4i*)(p + mt * 1024);
  };
  auto RDB = [&](int buf) {
    const int8_t* p = pB + buf * 16384;
    #pragma unroll
    for (int nt = 0; nt < 4; ++nt) b[nt] = *(const v4i*)(p + nt * 1024);
  };
  auto MM = [&](int m4) {   // T5: setprio around the 16-MFMA cluster
    __builtin_amdgcn_s_setprio(1);
    #pragma unroll
    for (int mt = 0; mt < 4; ++mt)
      #pragma unroll
      for (int nt = 0; nt < 4; ++nt)
        acc[m4 * 4 + mt][nt] =
            __builtin_amdgcn_mfma_i32_16x16x64_i8(a[mt], b[nt], acc[m4 * 4 + mt][nt], 0, 0, 0);
    __builtin_amdgcn_s_setprio(0);
  };

  const int NT = K >> 6;  // 64-B K-tiles (32 or 64)

  // prologue: kt0 -> buf0, kt1 -> buf1; drain kt0, keep kt1 in flight.
  SA(0, 0); SB(0, 0);
  SA(1, 1); SB(1, 1);
  VMC(4);
  BAR();

  int bk = 0, bs = 2;  // bk: buffer holding kt k; bs: buffer being staged (kt k+2)
  for (int k = 0; k < NT; ++k) {
    const bool st = (k + 2) < NT;

    // even phase: A(mt0-3) + B(nt0-3) reads; stage next A half-pair
    RDA(bk, 0); RDB(bk);
    if (st) SA(bs, k + 2);
    BAR(); MM(0); BAR();

    // odd phase: A(mt4-7) reads (B reused in regs); stage next B; gate for kt k+1
    RDA(bk, 1);
    if (st) {
      SB(bs, k + 2);
      VMC(4);             // outstanding 8: drains kt k+1's 4, keeps kt k+2's 4
    } else if (k + 1 < NT) {
      VMC(0);             // tail: drain kt k+1 fully
    }
    BAR(); MM(1); BAR();

    bk = (bk == 2) ? 0 : bk + 1;
    bs = (bs == 2) ? 0 : bs + 1;
  }

  // ---- epilogue: C/D layout (16x16): col = lane&15, row = (lane>>4)*4 + reg
  // acc[i] covers output rows (i>>2)*64 + (i&3)*16 of the wave's 128-row panel.
  const float wscale = (float)fmax(wsum[0] * invcnt, (double)EPSQ);
  const int crow_base = m0 + wr * 128 + (lane >> 4) * 4;
  const int ccol_base = n0 + wc * 64 + (lane & 15);
  #pragma unroll
  for (int mt = 0; mt < 8; ++mt) {
    const int trow = crow_base + (mt >> 2) * 64 + (mt & 3) * 16;
    float fr[4];
    #pragma unroll
    for (int r = 0; r < 4; ++r) fr[r] = wscale * invs[trow + r];
    #pragma unroll
    for (int nt = 0; nt < 4; ++nt) {
      const int col = ccol_base + nt * 16;
      #pragma unroll
      for (int r = 0; r < 4; ++r) {
        float v = (float)acc[mt][nt][r] * fr[r];
        if (RELU2) v = v > 0.f ? v * v : 0.f;
        if constexpr (sizeof(TOUT) == 2)
          C[(size_t)(trow + r) * N + col] = __float2half(v);
        else
          C[(size_t)(trow + r) * N + col] = v;
      }
    }
  }
}

extern "C" void kernel_launch(void* const* d_in, const int* in_sizes, int n_in,
                              void* d_out, int out_size, void* d_ws, size_t ws_size,
                              hipStream_t stream) {
  const float* x      = (const float*)d_in[0];   // (4,4096,2048)
  const float* w_up   = (const float*)d_in[1];   // (4096,2048)
  const float* w_down = (const float*)d_in[2];   // (2048,4096)
  float* out = (float*)d_out;

  const int T = in_sizes[0] / HIDDEN;            // 16384 tokens
  const size_t WN = (size_t)INTER * HIDDEN;      // 8388608 weights per matrix

  char* ws = (char*)d_ws;
  double* sums   = (double*)ws;                                   // [2]
  float* invs1   = (float*)(ws + 256);                            // [T]
  float* invs2   = (float*)(ws + 256 + 65536);                    // [T]
  int8_t* wq_up  = (int8_t*)(ws + 131328);                        // 8 MB
  int8_t* wq_dn  = wq_up + WN;                                    // 8 MB
  int8_t* a8_1   = wq_dn + WN;                                    // T*2048
  int8_t* a8_2   = a8_1 + (size_t)T * HIDDEN;                     // T*4096
  __half* h      = (__half*)(a8_2 + (size_t)T * INTER);           // T*4096 fp16

  const double invcnt = 1.0 / (double)WN;

  hipMemsetAsync(sums, 0, 256, stream);
  absmean_kernel<<<1024, 256, 0, stream>>>(w_up, WN / 4, sums + 0);
  absmean_kernel<<<1024, 256, 0, stream>>>(w_down, WN / 4, sums + 1);
  quantw_kernel<<<2048, 256, 0, stream>>>(w_up, WN / 4, sums + 0, invcnt, wq_up);
  quantw_kernel<<<2048, 256, 0, stream>>>(w_down, WN / 4, sums + 1, invcnt, wq_dn);

  fwht_quant_kernel<11, false><<<T / 4, 256, 0, stream>>>(x, a8_1, invs1);
  gemm_i8_3buf<true, __half><<<(T / 256) * (INTER / 256), 512, 0, stream>>>(
      a8_1, wq_up, h, invs1, sums + 0, invcnt, INTER, HIDDEN);
  fwht_quant_kernel<12, true><<<T / 4, 256, 0, stream>>>(h, a8_2, invs2);
  gemm_i8_3buf<false, float><<<(T / 256) * (HIDDEN / 256), 512, 0, stream>>>(
      a8_2, wq_dn, out, invs2, sums + 1, invcnt, HIDDEN, INTER);
}